// Round 5
// baseline (626.145 us; speedup 1.0000x reference)
//
#include <hip/hip_runtime.h>
#include <hip/hip_cooperative_groups.h>

namespace cg = cooperative_groups;

#define S_LEN 1024
#define HID   768
#define T_SZ  9
#define NEG_VAL (-1e12f)
#define NWG   1024

typedef __bf16 bf16x8 __attribute__((ext_vector_type(8)));
typedef float  f32x4  __attribute__((ext_vector_type(4)));
typedef short  short8 __attribute__((ext_vector_type(8)));
typedef short  short4v __attribute__((ext_vector_type(4)));
typedef float  float4v __attribute__((ext_vector_type(4)));

__device__ __forceinline__ unsigned short f2bf(float f) {
    unsigned int u = __builtin_bit_cast(unsigned int, f);
    u += 0x7FFFu + ((u >> 16) & 1u);          // RNE
    return (unsigned short)(u >> 16);
}

// async global->LDS, 16B per lane, linear dest (wave-uniform base + lane*16)
__device__ __forceinline__ void gload_lds16(const void* g, void* l) {
    __builtin_amdgcn_global_load_lds(
        (const __attribute__((address_space(1))) unsigned int*)g,
        (__attribute__((address_space(3))) unsigned int*)l,
        16, 0, 0);
}

union __align__(16) SmU {
    struct { unsigned short A[128 * 64]; unsigned short B[128 * 64]; } st;   // 32768 B
    unsigned short Tr[128 * 136];                                            // 34816 B
    struct { unsigned short As[128 * 64]; unsigned short Bs[128 * 64];
             int mi[128]; int mj[128]; } lg;                                 // 33792 B
};

// ---------- phase helpers (shared by mega + fallback kernels) ----------

__device__ __forceinline__ void do_convert(const float* __restrict__ src,
                                           unsigned short* __restrict__ dst, int i) {
    float4v a = *((const float4v*)src + (size_t)i * 2);
    float4v b = *((const float4v*)src + (size_t)i * 2 + 1);
    short8 o;
    o[0] = (short)f2bf(a[0]); o[1] = (short)f2bf(a[1]);
    o[2] = (short)f2bf(a[2]); o[3] = (short)f2bf(a[3]);
    o[4] = (short)f2bf(b[0]); o[5] = (short)f2bf(b[1]);
    o[6] = (short)f2bf(b[2]); o[7] = (short)f2bf(b[3]);
    *(short8*)(dst + (size_t)i * 8) = o;
}

__device__ __forceinline__ void do_table(float* __restrict__ cosT, float* __restrict__ sinT, int idx) {
    int s = idx >> 6;
    int d = idx & 63;
    float theta = exp2f(-13.2877123795f * (float)(d >> 1) * (1.0f / 32.0f)); // 10000^-(d/2)/32
    float ang = (float)s * theta;
    float sv, cv;
    sincosf(ang, &sv, &cv);
    cosT[idx] = cv;
    sinT[idx] = sv;
}

__device__ __forceinline__ void proj_tile(
    SmU& sm, int mt, int t,
    const unsigned short* __restrict__ hidB, const unsigned short* __restrict__ wB,
    const float* __restrict__ bias, const float* __restrict__ cosT, const float* __restrict__ sinT,
    unsigned short* __restrict__ qout, unsigned short* __restrict__ kout)
{
    int tid = threadIdx.x;
    int m0 = mt * 128;
    int n0 = t * 128;

    int lane = tid & 63;
    int wave = tid >> 6;
    int lr = lane & 15;
    int lq = lane >> 4;
    int wrow = wave * 32;

    float bv[8];
    #pragma unroll
    for (int fn = 0; fn < 8; ++fn) bv[fn] = bias[n0 + fn * 16 + lr];

    // per-lane pre-swizzled staging sources: linear LDS slot gsi holds data seg = slot ^ (r&7)
    const unsigned short* aSrc[4];
    const unsigned short* bSrc[4];
    #pragma unroll
    for (int it = 0; it < 4; ++it) {
        int gsi = (wave * 4 + it) * 64 + lane;
        int r = gsi >> 3;
        int sw = gsi & 7;
        int seg8 = (sw ^ (r & 7)) << 3;
        aSrc[it] = hidB + (size_t)(m0 + r) * HID + seg8;
        bSrc[it] = wB  + (size_t)(n0 + r) * HID + seg8;
    }

    f32x4 acc[2][8];
    #pragma unroll
    for (int i = 0; i < 2; ++i)
        #pragma unroll
        for (int j = 0; j < 8; ++j) acc[i][j] = (f32x4){0.f, 0.f, 0.f, 0.f};

    for (int kk = 0; kk < HID / 64; ++kk) {
        __syncthreads();
        #pragma unroll
        for (int it = 0; it < 4; ++it) {
            gload_lds16(aSrc[it] + kk * 64, &sm.st.A[(wave * 4 + it) * 512]);
            gload_lds16(bSrc[it] + kk * 64, &sm.st.B[(wave * 4 + it) * 512]);
        }
        __syncthreads();   // compiler drains vmcnt(0) before barrier
        #pragma unroll
        for (int kb = 0; kb < 2; ++kb) {
            bf16x8 af[2];
            #pragma unroll
            for (int fm = 0; fm < 2; ++fm) {
                int r = wrow + fm * 16 + lr;
                int seg = kb * 4 + lq;
                af[fm] = *(const bf16x8*)&sm.st.A[r * 64 + ((seg ^ (r & 7)) * 8)];
            }
            #pragma unroll
            for (int fn = 0; fn < 8; ++fn) {
                int r = fn * 16 + lr;
                int seg = kb * 4 + lq;
                bf16x8 bfr = *(const bf16x8*)&sm.st.B[r * 64 + ((seg ^ (r & 7)) * 8)];
                acc[0][fn] = __builtin_amdgcn_mfma_f32_16x16x32_bf16(af[0], bfr, acc[0][fn], 0, 0, 0);
                acc[1][fn] = __builtin_amdgcn_mfma_f32_16x16x32_bf16(af[1], bfr, acc[1][fn], 0, 0, 0);
            }
        }
    }
    __syncthreads();

    // bounce C (bias added) to col-major LDS bf16
    #pragma unroll
    for (int fm = 0; fm < 2; ++fm) {
        #pragma unroll
        for (int fn = 0; fn < 8; ++fn) {
            int col = fn * 16 + lr;
            int r0 = wrow + fm * 16 + lq * 4;
            short4v pk;
            #pragma unroll
            for (int j = 0; j < 4; ++j) pk[j] = (short)f2bf(acc[fm][fn][j] + bv[fn]);
            *(short4v*)&sm.Tr[col * 136 + r0] = pk;
        }
    }
    __syncthreads();

    // RoPE + transpose write: thread owns dim d for 32 rows
    int d = tid & 63;
    int grp = tid >> 6;
    int cq = 2 * d, ck = 2 * d + 1;
    int pq = (d < 32) ? (4 * d + 2) : (4 * (d - 32));
    int pk2 = pq + 1;
    float sgn = (d < 32) ? -1.0f : 1.0f;
    #pragma unroll
    for (int ch = 0; ch < 4; ++ch) {
        int r0 = grp * 32 + ch * 8;
        bf16x8 xq = *(const bf16x8*)&sm.Tr[cq * 136 + r0];
        bf16x8 xk = *(const bf16x8*)&sm.Tr[ck * 136 + r0];
        bf16x8 yq = *(const bf16x8*)&sm.Tr[pq * 136 + r0];
        bf16x8 yk = *(const bf16x8*)&sm.Tr[pk2 * 136 + r0];
        #pragma unroll
        for (int rr = 0; rr < 8; ++rr) {
            int gm = m0 + r0 + rr;
            int s  = gm & (S_LEN - 1);
            int bb = gm >> 10;
            float cv = cosT[s * 64 + d];
            float sv = sinT[s * 64 + d];
            float qv = (float)xq[rr] * cv + sgn * (float)yq[rr] * sv;
            float kv = (float)xk[rr] * cv + sgn * (float)yk[rr] * sv;
            size_t ob = (((size_t)bb * T_SZ + t) * S_LEN + s) * 64 + d;
            qout[ob] = f2bf(qv);
            kout[ob] = f2bf(kv);
        }
    }
    __syncthreads();
}

__device__ __forceinline__ void fill_tile(float* __restrict__ out, int bt, int ti, int tj) {
    size_t obase = ((size_t)bt * S_LEN + (size_t)ti * 128) * S_LEN + tj * 128;
    float4v nv = {NEG_VAL, NEG_VAL, NEG_VAL, NEG_VAL};
    #pragma unroll
    for (int it = 0; it < 16; ++it) {
        int idx = it * 256 + threadIdx.x;
        int r = idx >> 5;
        int c4 = idx & 31;
        __builtin_nontemporal_store(nv, (float4v*)&out[obase + (size_t)r * S_LEN + c4 * 4]);
    }
}

__device__ __forceinline__ void logits_tile(
    SmU& sm, const unsigned short* __restrict__ q, const unsigned short* __restrict__ k,
    const int* __restrict__ mask, float* __restrict__ out, int Bsz, int bt, int ti, int tj)
{
    int tid = threadIdx.x;
    size_t obase = ((size_t)bt * S_LEN + (size_t)ti * 128) * S_LEN + tj * 128;

    int b = bt / T_SZ;
    if (tid < 128) sm.lg.mi[tid] = mask[b * S_LEN + ti * 128 + tid];
    else           sm.lg.mj[tid - 128] = mask[b * S_LEN + tj * 128 + (tid - 128)];

    const unsigned short* qsrc = q + ((size_t)bt * S_LEN + (size_t)ti * 128) * 64;
    const unsigned short* ksrc = k + ((size_t)bt * S_LEN + (size_t)tj * 128) * 64;

    int lane = tid & 63;
    int wave = tid >> 6;
    #pragma unroll
    for (int it = 0; it < 4; ++it) {
        int gsi = (wave * 4 + it) * 64 + lane;
        int r = gsi >> 3;
        int sw = gsi & 7;
        int off = r * 64 + ((sw ^ (r & 7)) << 3);
        gload_lds16(qsrc + off, &sm.lg.As[(wave * 4 + it) * 512]);
        gload_lds16(ksrc + off, &sm.lg.Bs[(wave * 4 + it) * 512]);
    }
    __syncthreads();

    int lr = lane & 15;
    int lq = lane >> 4;
    int wrow = wave * 32;

    f32x4 acc[2][8];
    #pragma unroll
    for (int i = 0; i < 2; ++i)
        #pragma unroll
        for (int j = 0; j < 8; ++j) acc[i][j] = (f32x4){0.f, 0.f, 0.f, 0.f};

    // swapped operands: D = K.Q^T tile -> lane&15 = out ROW, reg idx = out COL
    #pragma unroll
    for (int kb = 0; kb < 2; ++kb) {
        bf16x8 qf[2];
        #pragma unroll
        for (int fi = 0; fi < 2; ++fi) {
            int r = wrow + fi * 16 + lr;
            int seg = kb * 4 + lq;
            qf[fi] = *(const bf16x8*)&sm.lg.As[r * 64 + ((seg ^ (r & 7)) * 8)];
        }
        #pragma unroll
        for (int fn = 0; fn < 8; ++fn) {
            int r = fn * 16 + lr;
            int seg = kb * 4 + lq;
            bf16x8 kf = *(const bf16x8*)&sm.lg.Bs[r * 64 + ((seg ^ (r & 7)) * 8)];
            acc[0][fn] = __builtin_amdgcn_mfma_f32_16x16x32_bf16(kf, qf[0], acc[0][fn], 0, 0, 0);
            acc[1][fn] = __builtin_amdgcn_mfma_f32_16x16x32_bf16(kf, qf[1], acc[1][fn], 0, 0, 0);
        }
    }

    #pragma unroll
    for (int fi = 0; fi < 2; ++fi) {
        int il = wrow + fi * 16 + lr;
        int gi = ti * 128 + il;
        bool mrow = sm.lg.mi[il] != 0;
        size_t rbase = obase + (size_t)il * S_LEN;
        #pragma unroll
        for (int fn = 0; fn < 8; ++fn) {
            int j0 = fn * 16 + lq * 4;
            int gj0 = tj * 128 + j0;
            float4v v;
            #pragma unroll
            for (int e = 0; e < 4; ++e) {
                bool ok = mrow && (sm.lg.mj[j0 + e] != 0) && (gi <= gj0 + e);
                v[e] = ok ? acc[fi][fn][e] : NEG_VAL;
            }
            __builtin_nontemporal_store(v, (float4v*)&out[rbase + j0]);
        }
    }
    __syncthreads();   // LDS reuse guard for next tile
}

// ---------------- cooperative mega-kernel ----------------
__global__ __launch_bounds__(256, 4) void mega(
    const float* __restrict__ hidden, const int* __restrict__ mask,
    const float* __restrict__ W, const float* __restrict__ bias,
    float* __restrict__ out, float* cosT, float* sinT,
    unsigned short* hidB, unsigned short* wB,
    unsigned short* qb, unsigned short* kb,
    int Bsz, int n8h, int n8w)
{
    __shared__ SmU sm;
    cg::grid_group grid = cg::this_grid();

    // phase A: convert hidden+W to bf16, build rope tables
    int gtid = blockIdx.x * 256 + threadIdx.x;
    int gs   = gridDim.x * 256;
    for (int i = gtid; i < n8h; i += gs) do_convert(hidden, hidB, i);
    for (int i = gtid; i < n8w; i += gs) do_convert(W, wB, i);
    for (int i = gtid; i < S_LEN * 64; i += gs) do_table(cosT, sinT, i);
    grid.sync();

    // phase B: projection GEMM+RoPE on blocks [0,nproj); NEG-fill rides on the rest
    int nproj = Bsz * 72;                 // always %8 == 0
    for (int b2 = blockIdx.x; b2 < nproj; b2 += gridDim.x) {
        int tile = (b2 & 7) * (nproj >> 3) + (b2 >> 3);   // XCD-chunked
        proj_tile(sm, tile / T_SZ, tile % T_SZ, hidB, wB, bias, cosT, sinT, qb, kb);
    }
    {
        int nf = Bsz * T_SZ * 28;         // strictly-below-diagonal tiles
        int fillStart, fillStride;
        if (nproj < (int)gridDim.x) { fillStart = (int)blockIdx.x - nproj; fillStride = (int)gridDim.x - nproj; }
        else                        { fillStart = (int)blockIdx.x;          fillStride = (int)gridDim.x; }
        if (fillStart >= 0)
            for (int f = fillStart; f < nf; f += fillStride) {
                int bt = f / 28, rr = f % 28;
                int ti = 1; while (rr >= ti) { rr -= ti; ++ti; }
                fill_tile(out, bt, ti, rr);
            }
    }
    grid.sync();

    // phase C: logits compute tiles (ti<=tj), XCD-chunked
    int ncomp = Bsz * T_SZ * 36;
    int cc = ncomp >> 3;
    for (int x = blockIdx.x; x < ncomp; x += gridDim.x) {
        int c = ((ncomp & 7) == 0) ? ((x & 7) * cc + (x >> 3)) : x;
        int bt = c / 36, r = c % 36;
        int ti = 0; while (r >= 8 - ti) { r -= 8 - ti; ++ti; }
        logits_tile(sm, qb, kb, mask, out, Bsz, bt, ti, ti + r);
    }
}

// ---------------- fallback kernels (non-cooperative path) ----------------
__global__ __launch_bounds__(256) void k_convert_fb(const float* __restrict__ src,
                                                    unsigned short* __restrict__ dst, int n8) {
    int i = blockIdx.x * 256 + threadIdx.x;
    if (i < n8) do_convert(src, dst, i);
}

__global__ void k_tables_fb(float* cosT, float* sinT) {
    do_table(cosT, sinT, blockIdx.x * 256 + threadIdx.x);
}

__global__ __launch_bounds__(256) void k_proj_fb(
    const unsigned short* __restrict__ hidB, const unsigned short* __restrict__ wB,
    const float* __restrict__ bias, const float* __restrict__ cosT, const float* __restrict__ sinT,
    unsigned short* __restrict__ qb, unsigned short* __restrict__ kb)
{
    __shared__ SmU sm;
    int npj = gridDim.x;
    int b = blockIdx.x;
    int tile = ((npj & 7) == 0) ? ((b & 7) * (npj >> 3) + (b >> 3)) : b;
    proj_tile(sm, tile / T_SZ, tile % T_SZ, hidB, wB, bias, cosT, sinT, qb, kb);
}

__global__ __launch_bounds__(256) void k_logits_fb(
    const unsigned short* __restrict__ q, const unsigned short* __restrict__ k,
    const int* __restrict__ mask, float* __restrict__ out, int Bsz)
{
    __shared__ SmU sm;
    int bt  = blockIdx.x >> 6;
    int rem = blockIdx.x & 63;
    int ti = rem >> 3;
    int tj = rem & 7;
    if (ti > tj) fill_tile(out, bt, ti, tj);
    else         logits_tile(sm, q, k, mask, out, Bsz, bt, ti, tj);
}

extern "C" void kernel_launch(void* const* d_in, const int* in_sizes, int n_in,
                              void* d_out, int out_size, void* d_ws, size_t ws_size,
                              hipStream_t stream) {
    const float* hidden = (const float*)d_in[0];
    const int*   mask   = (const int*)d_in[1];
    const float* W      = (const float*)d_in[2];
    const float* bias   = (const float*)d_in[3];
    float* out = (float*)d_out;
    int Bsz = in_sizes[0] / (S_LEN * HID);

    char* ws = (char*)d_ws;
    float* cosT = (float*)ws;
    float* sinT = (float*)(ws + (size_t)S_LEN * 64 * 4);
    unsigned short* hidB = (unsigned short*)(ws + 2ull * S_LEN * 64 * 4);
    size_t hidElems = (size_t)Bsz * S_LEN * HID;
    unsigned short* wB = hidB + hidElems;
    size_t wElems = (size_t)2 * T_SZ * 64 * HID;
    unsigned short* qb = wB + wElems;
    size_t qkElems = (size_t)Bsz * T_SZ * S_LEN * 64;
    unsigned short* kb = qb + qkElems;

    int n8h = (int)(hidElems / 8);
    int n8w = (int)(wElems / 8);

    void* args[] = { (void*)&hidden, (void*)&mask, (void*)&W, (void*)&bias,
                     (void*)&out, (void*)&cosT, (void*)&sinT,
                     (void*)&hidB, (void*)&wB, (void*)&qb, (void*)&kb,
                     (void*)&Bsz, (void*)&n8h, (void*)&n8w };
    hipError_t err = hipLaunchCooperativeKernel((const void*)mega, dim3(NWG), dim3(256),
                                                args, 0, stream);
    if (err != hipSuccess) {
        // fallback: serial 5-kernel pipeline (verified in round 4)
        k_convert_fb<<<dim3((n8h + 255) / 256), dim3(256), 0, stream>>>(hidden, hidB, n8h);
        k_convert_fb<<<dim3((n8w + 255) / 256), dim3(256), 0, stream>>>(W, wB, n8w);
        k_tables_fb<<<dim3(S_LEN * 64 / 256), dim3(256), 0, stream>>>(cosT, sinT);
        k_proj_fb<<<dim3(Bsz * 72), dim3(256), 0, stream>>>(hidB, wB, bias, cosT, sinT, qb, kb);
        k_logits_fb<<<dim3(Bsz * T_SZ * 64), dim3(256), 0, stream>>>(qb, kb, mask, out, Bsz);
    }
}

// Round 6
// 381.652 us; speedup vs baseline: 1.6406x; 1.6406x over previous
//
#include <hip/hip_runtime.h>

#define S_LEN 1024
#define HID   768
#define T_SZ  9
#define NEG_VAL (-1e12f)

typedef __bf16 bf16x8 __attribute__((ext_vector_type(8)));
typedef float  f32x4  __attribute__((ext_vector_type(4)));
typedef short  short8 __attribute__((ext_vector_type(8)));
typedef short  short4v __attribute__((ext_vector_type(4)));
typedef float  float4v __attribute__((ext_vector_type(4)));

__device__ __forceinline__ unsigned short f2bf(float f) {
    unsigned int u = __builtin_bit_cast(unsigned int, f);
    u += 0x7FFFu + ((u >> 16) & 1u);          // RNE
    return (unsigned short)(u >> 16);
}

// async global->LDS, 16B per lane, linear dest (wave-uniform base + lane*16)
__device__ __forceinline__ void gload_lds16(const void* g, void* l) {
    __builtin_amdgcn_global_load_lds(
        (const __attribute__((address_space(1))) unsigned int*)g,
        (__attribute__((address_space(3))) unsigned int*)l,
        16, 0, 0);
}

__device__ __forceinline__ void do_convert(const float* __restrict__ src,
                                           unsigned short* __restrict__ dst, int i) {
    float4v a = *((const float4v*)src + (size_t)i * 2);
    float4v b = *((const float4v*)src + (size_t)i * 2 + 1);
    short8 o;
    o[0] = (short)f2bf(a[0]); o[1] = (short)f2bf(a[1]);
    o[2] = (short)f2bf(a[2]); o[3] = (short)f2bf(a[3]);
    o[4] = (short)f2bf(b[0]); o[5] = (short)f2bf(b[1]);
    o[6] = (short)f2bf(b[2]); o[7] = (short)f2bf(b[3]);
    *(short8*)(dst + (size_t)i * 8) = o;
}

// ---------------- kernel 1: converts + rope tables, one launch ----------------
__global__ __launch_bounds__(256) void k_prep(
    const float* __restrict__ hidden, const float* __restrict__ W,
    unsigned short* __restrict__ hidB, unsigned short* __restrict__ wB,
    float* __restrict__ cosT, float* __restrict__ sinT, int n8h, int n8w)
{
    int i = blockIdx.x * 256 + threadIdx.x;
    if (i < n8h) { do_convert(hidden, hidB, i); return; }
    i -= n8h;
    if (i < n8w) { do_convert(W, wB, i); return; }
    i -= n8w;
    if (i < S_LEN * 64) {
        int s = i >> 6;
        int d = i & 63;
        float theta = exp2f(-13.2877123795f * (float)(d >> 1) * (1.0f / 32.0f)); // 10000^(-(d/2)/32)
        float ang = (float)s * theta;
        float sv, cv;
        sincosf(ang, &sv, &cv);
        cosT[i] = cv;
        sinT[i] = sv;
    }
}

// ---------------- kernel 2: proj GEMM (2-phase dbuf) + RoPE, fill tiles merged ----------------
union __align__(16) SmP {
    unsigned short buf[2][2][128 * 64];   // [parity][A=0/B=1][row*64 + swz]  = 64 KB
    unsigned short Tr[128 * 136];         // col-major C bounce, 34.8 KB
};

__global__ __launch_bounds__(256) void k_proj_fill(
    const unsigned short* __restrict__ hidB,   // [B*S][768] bf16
    const unsigned short* __restrict__ wB,     // [1152][768] bf16
    const float* __restrict__ bias,
    const float* __restrict__ cosT,
    const float* __restrict__ sinT,
    unsigned short* __restrict__ qout,
    unsigned short* __restrict__ kout,
    float* __restrict__ out, int nproj)
{
    __shared__ SmP sm;
    int tid = threadIdx.x;
    int blk = blockIdx.x;

    if (blk >= nproj) {
        // strictly-below-diagonal NEG fill, overlapped with proj compute
        int f = blk - nproj;
        int bt = f / 28, rr = f % 28;
        int ti = 1; while (rr >= ti) { rr -= ti; ++ti; }
        size_t obase = ((size_t)bt * S_LEN + (size_t)ti * 128) * S_LEN + rr * 128;
        float4v nv = {NEG_VAL, NEG_VAL, NEG_VAL, NEG_VAL};
        #pragma unroll
        for (int it = 0; it < 16; ++it) {
            int idx = it * 256 + tid;
            int r = idx >> 5;
            int c4 = idx & 31;
            __builtin_nontemporal_store(nv, (float4v*)&out[obase + (size_t)r * S_LEN + c4 * 4]);
        }
        return;
    }

    int mt = blk / T_SZ;
    int t  = blk % T_SZ;
    int m0 = mt * 128;
    int n0 = t * 128;

    int lane = tid & 63;
    int wave = tid >> 6;
    int lr = lane & 15;
    int lq = lane >> 4;
    int wrow = wave * 32;

    float bv[8];
    #pragma unroll
    for (int fn = 0; fn < 8; ++fn) bv[fn] = bias[n0 + fn * 16 + lr];

    // per-lane pre-swizzled staging sources: linear LDS slot gsi holds data seg = slot ^ (r&7)
    const unsigned short* aSrc[4];
    const unsigned short* bSrc[4];
    #pragma unroll
    for (int it = 0; it < 4; ++it) {
        int gsi = (wave * 4 + it) * 64 + lane;
        int r = gsi >> 3;
        int sw = gsi & 7;
        int seg8 = (sw ^ (r & 7)) << 3;
        aSrc[it] = hidB + (size_t)(m0 + r) * HID + seg8;
        bSrc[it] = wB  + (size_t)(n0 + r) * HID + seg8;
    }

    f32x4 acc[2][8];
    #pragma unroll
    for (int i = 0; i < 2; ++i)
        #pragma unroll
        for (int j = 0; j < 8; ++j) acc[i][j] = (f32x4){0.f, 0.f, 0.f, 0.f};

    // prologue stage
    #pragma unroll
    for (int it = 0; it < 4; ++it) {
        gload_lds16(aSrc[it], &sm.buf[0][0][(wave * 4 + it) * 512]);
        gload_lds16(bSrc[it], &sm.buf[0][1][(wave * 4 + it) * 512]);
    }
    __syncthreads();

    for (int kk = 0; kk < HID / 64; ++kk) {
        int par = kk & 1;
        if (kk < HID / 64 - 1) {       // issue next K-step's loads; latency hides under MFMA
            #pragma unroll
            for (int it = 0; it < 4; ++it) {
                gload_lds16(aSrc[it] + (kk + 1) * 64, &sm.buf[par ^ 1][0][(wave * 4 + it) * 512]);
                gload_lds16(bSrc[it] + (kk + 1) * 64, &sm.buf[par ^ 1][1][(wave * 4 + it) * 512]);
            }
        }
        #pragma unroll
        for (int kb = 0; kb < 2; ++kb) {
            bf16x8 af[2];
            #pragma unroll
            for (int fm = 0; fm < 2; ++fm) {
                int r = wrow + fm * 16 + lr;
                int seg = kb * 4 + lq;
                af[fm] = *(const bf16x8*)&sm.buf[par][0][r * 64 + ((seg ^ (r & 7)) * 8)];
            }
            #pragma unroll
            for (int fn = 0; fn < 8; ++fn) {
                int r = fn * 16 + lr;
                int seg = kb * 4 + lq;
                bf16x8 bfr = *(const bf16x8*)&sm.buf[par][1][r * 64 + ((seg ^ (r & 7)) * 8)];
                acc[0][fn] = __builtin_amdgcn_mfma_f32_16x16x32_bf16(af[0], bfr, acc[0][fn], 0, 0, 0);
                acc[1][fn] = __builtin_amdgcn_mfma_f32_16x16x32_bf16(af[1], bfr, acc[1][fn], 0, 0, 0);
            }
        }
        __syncthreads();   // drains vmcnt(0): next buffer ready; reads of cur done
    }

    // bounce C (bias added) to col-major LDS bf16 (aliases staging bufs — safe after barrier)
    #pragma unroll
    for (int fm = 0; fm < 2; ++fm) {
        #pragma unroll
        for (int fn = 0; fn < 8; ++fn) {
            int col = fn * 16 + lr;
            int r0 = wrow + fm * 16 + lq * 4;
            short4v pk;
            #pragma unroll
            for (int j = 0; j < 4; ++j) pk[j] = (short)f2bf(acc[fm][fn][j] + bv[fn]);
            *(short4v*)&sm.Tr[col * 136 + r0] = pk;
        }
    }
    __syncthreads();

    // RoPE + transpose write: thread owns dim d for 32 rows
    int d = tid & 63;
    int grp = tid >> 6;
    int cq = 2 * d, ck = 2 * d + 1;
    int pq = (d < 32) ? (4 * d + 2) : (4 * (d - 32));
    int pk2 = pq + 1;
    float sgn = (d < 32) ? -1.0f : 1.0f;
    #pragma unroll
    for (int ch = 0; ch < 4; ++ch) {
        int r0 = grp * 32 + ch * 8;
        bf16x8 xq = *(const bf16x8*)&sm.Tr[cq * 136 + r0];
        bf16x8 xk = *(const bf16x8*)&sm.Tr[ck * 136 + r0];
        bf16x8 yq = *(const bf16x8*)&sm.Tr[pq * 136 + r0];
        bf16x8 yk = *(const bf16x8*)&sm.Tr[pk2 * 136 + r0];
        #pragma unroll
        for (int rr = 0; rr < 8; ++rr) {
            int gm = m0 + r0 + rr;
            int s  = gm & (S_LEN - 1);
            int bb = gm >> 10;
            float cv = cosT[s * 64 + d];
            float sv = sinT[s * 64 + d];
            float qv = (float)xq[rr] * cv + sgn * (float)yq[rr] * sv;
            float kv = (float)xk[rr] * cv + sgn * (float)yk[rr] * sv;
            size_t ob = (((size_t)bb * T_SZ + t) * S_LEN + s) * 64 + d;
            qout[ob] = f2bf(qv);
            kout[ob] = f2bf(kv);
        }
    }
}

// ---------------- kernel 3: logits compute tiles only (ti<=tj) ----------------
__global__ __launch_bounds__(256) void k_logits(
    const unsigned short* __restrict__ q,
    const unsigned short* __restrict__ k,
    const int* __restrict__ mask,
    float* __restrict__ out)
{
    __shared__ __align__(16) unsigned short As[128 * 64];
    __shared__ __align__(16) unsigned short Bs[128 * 64];
    __shared__ int mi[128], mj[128];

    int tid = threadIdx.x;
    int c = blockIdx.x;
    int bt = c / 36, r = c % 36;
    int ti = 0; while (r >= 8 - ti) { r -= 8 - ti; ++ti; }
    int tj = ti + r;
    size_t obase = ((size_t)bt * S_LEN + (size_t)ti * 128) * S_LEN + tj * 128;

    int b = bt / T_SZ;
    if (tid < 128) mi[tid] = mask[b * S_LEN + ti * 128 + tid];
    else           mj[tid - 128] = mask[b * S_LEN + tj * 128 + (tid - 128)];

    const unsigned short* qsrc = q + ((size_t)bt * S_LEN + (size_t)ti * 128) * 64;
    const unsigned short* ksrc = k + ((size_t)bt * S_LEN + (size_t)tj * 128) * 64;

    int lane = tid & 63;
    int wave = tid >> 6;
    #pragma unroll
    for (int it = 0; it < 4; ++it) {
        int gsi = (wave * 4 + it) * 64 + lane;
        int rr = gsi >> 3;
        int sw = gsi & 7;
        int off = rr * 64 + ((sw ^ (rr & 7)) << 3);
        gload_lds16(qsrc + off, &As[(wave * 4 + it) * 512]);
        gload_lds16(ksrc + off, &Bs[(wave * 4 + it) * 512]);
    }
    __syncthreads();

    int lr = lane & 15;
    int lq = lane >> 4;
    int wrow = wave * 32;

    f32x4 acc[2][8];
    #pragma unroll
    for (int i = 0; i < 2; ++i)
        #pragma unroll
        for (int j = 0; j < 8; ++j) acc[i][j] = (f32x4){0.f, 0.f, 0.f, 0.f};

    // swapped operands: D = K.Q^T tile -> lane&15 = out ROW, reg idx = out COL
    #pragma unroll
    for (int kb = 0; kb < 2; ++kb) {
        bf16x8 qf[2];
        #pragma unroll
        for (int fi = 0; fi < 2; ++fi) {
            int rr = wrow + fi * 16 + lr;
            int seg = kb * 4 + lq;
            qf[fi] = *(const bf16x8*)&As[rr * 64 + ((seg ^ (rr & 7)) * 8)];
        }
        #pragma unroll
        for (int fn = 0; fn < 8; ++fn) {
            int rr = fn * 16 + lr;
            int seg = kb * 4 + lq;
            bf16x8 kf = *(const bf16x8*)&Bs[rr * 64 + ((seg ^ (rr & 7)) * 8)];
            acc[0][fn] = __builtin_amdgcn_mfma_f32_16x16x32_bf16(kf, qf[0], acc[0][fn], 0, 0, 0);
            acc[1][fn] = __builtin_amdgcn_mfma_f32_16x16x32_bf16(kf, qf[1], acc[1][fn], 0, 0, 0);
        }
    }

    #pragma unroll
    for (int fi = 0; fi < 2; ++fi) {
        int il = wrow + fi * 16 + lr;
        int gi = ti * 128 + il;
        bool mrow = mi[il] != 0;
        size_t rbase = obase + (size_t)il * S_LEN;
        #pragma unroll
        for (int fn = 0; fn < 8; ++fn) {
            int j0 = fn * 16 + lq * 4;
            int gj0 = tj * 128 + j0;
            float4v v;
            #pragma unroll
            for (int e = 0; e < 4; ++e) {
                bool ok = mrow && (mj[j0 + e] != 0) && (gi <= gj0 + e);
                v[e] = ok ? acc[fi][fn][e] : NEG_VAL;
            }
            __builtin_nontemporal_store(v, (float4v*)&out[rbase + j0]);
        }
    }
}

extern "C" void kernel_launch(void* const* d_in, const int* in_sizes, int n_in,
                              void* d_out, int out_size, void* d_ws, size_t ws_size,
                              hipStream_t stream) {
    const float* hidden = (const float*)d_in[0];
    const int*   mask   = (const int*)d_in[1];
    const float* W      = (const float*)d_in[2];
    const float* bias   = (const float*)d_in[3];
    float* out = (float*)d_out;
    int Bsz = in_sizes[0] / (S_LEN * HID);

    char* ws = (char*)d_ws;
    float* cosT = (float*)ws;
    float* sinT = (float*)(ws + (size_t)S_LEN * 64 * 4);
    unsigned short* hidB = (unsigned short*)(ws + 2ull * S_LEN * 64 * 4);
    size_t hidElems = (size_t)Bsz * S_LEN * HID;
    unsigned short* wB = hidB + hidElems;
    size_t wElems = (size_t)2 * T_SZ * 64 * HID;
    unsigned short* qb = wB + wElems;
    size_t qkElems = (size_t)Bsz * T_SZ * S_LEN * 64;
    unsigned short* kb = qb + qkElems;

    int n8h = (int)(hidElems / 8);
    int n8w = (int)(wElems / 8);
    int nPrep = (n8h + n8w + S_LEN * 64 + 255) / 256;
    int nproj = Bsz * 72;                       // 128-row tiles * 9 t-blocks
    int nfill = Bsz * T_SZ * 28;                // strictly-below-diagonal tiles
    int ncomp = Bsz * T_SZ * 36;                // ti<=tj tiles

    k_prep<<<dim3(nPrep), dim3(256), 0, stream>>>(hidden, W, hidB, wB, cosT, sinT, n8h, n8w);
    k_proj_fill<<<dim3(nproj + nfill), dim3(256), 0, stream>>>(hidB, wB, bias, cosT, sinT,
                                                               qb, kb, out, nproj);
    k_logits<<<dim3(ncomp), dim3(256), 0, stream>>>(qb, kb, mask, out);
}